// Round 4
// baseline (340.300 us; speedup 1.0000x reference)
//
#include <hip/hip_runtime.h>
#include <hip/hip_bf16.h>
#include <stdint.h>

// SurrealEmbedding: B=8192, L=618, D=1910
// Decomposition: base[s] = S + sigma*D, S=(p+m)/2, D=(p-m)/2, sigma=+-1.
// hv[b] = P[n_b] + sum_l A_D[b,l] * D_l   (P = fp32 prefix table over S)
#define B_   8192
#define L_   618
#define D_   1910
#define KA   640          // K for the D-GEMM (padded L, multiple of 64)
#define NP   1920         // padded D (multiple of 128)
#define PSTRIDE 1920

#define ALPHA_F 0.61803400516510009765625f   // float32(1/phi), exact bits

typedef __attribute__((ext_vector_type(8))) short short8;
typedef __attribute__((ext_vector_type(4))) float f32x4;

__device__ __forceinline__ unsigned short f2bf(float f) {
  union { float f; unsigned u; } v; v.f = f;
  unsigned u = v.u;
  return (unsigned short)((u + 0x7FFFu + ((u >> 16) & 1u)) >> 16);  // RNE
}

// ---------------------------------------------------------------------------
// prep_A: A_D[b][l] = (l<n) ? sigma*w_l : 0   (bf16; w_0=ALPHA, w_{l>=1}=1.0)
// ---------------------------------------------------------------------------
__global__ void prep_A(const int* __restrict__ signs, const int* __restrict__ lengths,
                       unsigned short* __restrict__ A) {
  int b = blockIdx.x;
  int n = lengths[b];
  const unsigned short w1 = 0x3F80u;          // bf16(1.0)
  const unsigned short wa = f2bf(ALPHA_F);    // bf16(ALPHA)
  for (int l = threadIdx.x; l < KA; l += blockDim.x) {
    unsigned short val = 0;
    if (l < L_ && l < n) {
      unsigned short w = (l == 0) ? wa : w1;
      int s = signs[b * L_ + l];
      val = s ? (unsigned short)(w | 0x8000u) : w;   // minus -> -w
    }
    A[(size_t)b * KA + l] = val;
  }
}

// ---------------------------------------------------------------------------
// prep_B: BT[d][l] = bf16((bp[l][d]-bm[l][d])/2), transposed via LDS tile so
// both global reads and writes are coalesced.  BT is [NP][KA] bf16.
// ---------------------------------------------------------------------------
__global__ void prep_B(const float* __restrict__ bp, const float* __restrict__ bm,
                       unsigned short* __restrict__ BT) {
  __shared__ unsigned short tile[64][65];
  int lt = threadIdx.x & 63;
  int wt = threadIdx.x >> 6;       // 0..3
  int l0 = blockIdx.y * 64, d0 = blockIdx.x * 64;
#pragma unroll
  for (int i = 0; i < 16; ++i) {
    int r = i * 4 + wt;            // l-offset within tile
    int l = l0 + r, d = d0 + lt;
    unsigned short v = 0;
    if (l < L_ && d < D_)
      v = f2bf(0.5f * (bp[(size_t)l * D_ + d] - bm[(size_t)l * D_ + d]));
    tile[lt][r] = v;               // [d-idx][l-idx]
  }
  __syncthreads();
#pragma unroll
  for (int i = 0; i < 16; ++i) {
    int rd = i * 4 + wt;           // d-offset within tile
    BT[(size_t)(d0 + rd) * KA + l0 + lt] = tile[rd][lt];
  }
}

// ---------------------------------------------------------------------------
// prefix_P: P[n][d] = ALPHA*S_0[d] + sum_{1<=l<n} S_l[d],  n in [1, 640].
// Chunked over n (5 chunks x 128) so blocks recompute only their prefix.
// ---------------------------------------------------------------------------
__global__ void prefix_P(const float* __restrict__ bp, const float* __restrict__ bm,
                         float* __restrict__ P) {
  int d = blockIdx.x * 256 + threadIdx.x;
  if (d >= D_) return;
  int nc = blockIdx.y;                    // 0..4
  int n_start = nc * 128 + 1;
  int n_end = (nc + 1) * 128;             // write n in [n_start, n_end]
  float acc = 0.f;
  for (int l = 0; l < n_end; ++l) {
    if (l < L_) {
      float s = 0.5f * (bp[(size_t)l * D_ + d] + bm[(size_t)l * D_ + d]);
      acc += (l == 0) ? ALPHA_F * s : s;
    }
    int n = l + 1;
    if (n >= n_start) P[(size_t)n * PSTRIDE + d] = acc;
  }
}

// ---------------------------------------------------------------------------
// GEMM: C[8192][1920] = A_D[8192][640] * D[640][1920] (D given transposed).
// 128x128 tile, BK=64, 4 waves of 64x64, 16x16x32 bf16 MFMA, XOR-swizzled LDS.
// ---------------------------------------------------------------------------
__global__ __launch_bounds__(256)
void gemm_kernel(const unsigned short* __restrict__ A2,
                 const unsigned short* __restrict__ BT,
                 float* __restrict__ out) {
  __shared__ __align__(16) short As[128 * 64];
  __shared__ __align__(16) short Bs[128 * 64];

  const int tid = threadIdx.x;
  const int l   = tid & 63;
  const int w   = tid >> 6;
  const int wm  = w >> 1, wn = w & 1;
  const int m0  = blockIdx.y * 128;
  const int n0  = blockIdx.x * 128;

  f32x4 acc[4][4] = {};
  short8 ar[4], br[4];

#pragma unroll
  for (int i = 0; i < 4; ++i) {
    int idx = (i * 256 + tid) * 8;
    int r = idx >> 6, c = idx & 63;
    ar[i] = *(const short8*)(A2 + (size_t)(m0 + r) * KA + c);
    br[i] = *(const short8*)(BT + (size_t)(n0 + r) * KA + c);
  }

  const int NT = KA / 64;
  for (int kt = 0; kt < NT; ++kt) {
    __syncthreads();
#pragma unroll
    for (int i = 0; i < 4; ++i) {
      int idx = (i * 256 + tid) * 8;
      int r = idx >> 6;
      int off = idx ^ ((r & 7) << 3);      // T2 swizzle, 16B slots (short units)
      *(short8*)(As + off) = ar[i];
      *(short8*)(Bs + off) = br[i];
    }
    __syncthreads();

    if (kt + 1 < NT) {
      int k0 = (kt + 1) * 64;
#pragma unroll
      for (int i = 0; i < 4; ++i) {
        int idx = (i * 256 + tid) * 8;
        int r = idx >> 6, c = idx & 63;
        ar[i] = *(const short8*)(A2 + (size_t)(m0 + r) * KA + k0 + c);
        br[i] = *(const short8*)(BT + (size_t)(n0 + r) * KA + k0 + c);
      }
    }

#pragma unroll
    for (int kk = 0; kk < 64; kk += 32) {
      const int cs = kk + ((l >> 4) << 3);        // short col within tile row
      short8 af[4], bf[4];
#pragma unroll
      for (int m = 0; m < 4; ++m) {
        int r = wm * 64 + m * 16 + (l & 15);
        af[m] = *(const short8*)(As + (r * 64 + (cs ^ ((r & 7) << 3))));
      }
#pragma unroll
      for (int n = 0; n < 4; ++n) {
        int r = wn * 64 + n * 16 + (l & 15);
        bf[n] = *(const short8*)(Bs + (r * 64 + (cs ^ ((r & 7) << 3))));
      }
#pragma unroll
      for (int m = 0; m < 4; ++m)
#pragma unroll
        for (int n = 0; n < 4; ++n)
          acc[m][n] = __builtin_amdgcn_mfma_f32_16x16x32_bf16(af[m], bf[n], acc[m][n], 0, 0, 0);
    }
  }

  // epilogue: C/D layout col = lane&15, row = (lane>>4)*4 + reg
  const int rl = l >> 4, cl = l & 15;
#pragma unroll
  for (int m = 0; m < 4; ++m) {
#pragma unroll
    for (int n = 0; n < 4; ++n) {
      int col = n0 + wn * 64 + n * 16 + cl;
      if (col < D_) {
        int rbase = m0 + wm * 64 + m * 16 + rl * 4;
#pragma unroll
        for (int q = 0; q < 4; ++q)
          out[(size_t)(rbase + q) * D_ + col] = acc[m][n][q];
      }
    }
  }
}

// ---------------------------------------------------------------------------
// normalize: v = gemm_out[b,:] + P[n_b,:];  out = v / max(||v||, eps-guard)
// ---------------------------------------------------------------------------
__global__ void normalize_kernel(float* __restrict__ out, const int* __restrict__ lengths,
                                 const float* __restrict__ P) {
  __shared__ float red[4];
  int b = blockIdx.x;
  int n = lengths[b];
  float* row = out + (size_t)b * D_;
  const float* prow = P + (size_t)n * PSTRIDE;
  float vals[8];
  float ss = 0.f;
#pragma unroll
  for (int j = 0; j < 8; ++j) {
    int d = threadIdx.x + j * 256;
    float v = 0.f;
    if (d < D_) v = row[d] + prow[d];
    vals[j] = v;
    ss += v * v;
  }
#pragma unroll
  for (int off = 32; off > 0; off >>= 1)
    ss += __shfl_down(ss, off, 64);
  int lane = threadIdx.x & 63, wv = threadIdx.x >> 6;
  if (lane == 0) red[wv] = ss;
  __syncthreads();
  float tot = red[0] + red[1] + red[2] + red[3];
  float inv = (tot > 0.f) ? (1.0f / sqrtf(tot)) : 1.0f;
#pragma unroll
  for (int j = 0; j < 8; ++j) {
    int d = threadIdx.x + j * 256;
    if (d < D_) row[d] = vals[j] * inv;
  }
}

extern "C" void kernel_launch(void* const* d_in, const int* in_sizes, int n_in,
                              void* d_out, int out_size, void* d_ws, size_t ws_size,
                              hipStream_t stream) {
  const int*   signs   = (const int*)d_in[0];
  const int*   lengths = (const int*)d_in[1];
  const float* bp      = (const float*)d_in[2];
  const float* bm      = (const float*)d_in[3];
  float*       out     = (float*)d_out;

  unsigned short* A  = (unsigned short*)d_ws;                 // [8192][640] bf16 = 10.49 MB
  unsigned short* BT = A + (size_t)B_ * KA;                   // [1920][640] bf16 =  2.46 MB
  float*          P  = (float*)(BT + (size_t)NP * KA);        // [656][1920] f32  =  5.04 MB

  prep_A<<<B_, 256, 0, stream>>>(signs, lengths, A);
  prep_B<<<dim3(NP / 64, KA / 64), 256, 0, stream>>>(bp, bm, BT);
  prefix_P<<<dim3(8, 5), 256, 0, stream>>>(bp, bm, P);
  gemm_kernel<<<dim3(NP / 128, B_ / 128), 256, 0, stream>>>(A, BT, out);
  normalize_kernel<<<B_, 256, 0, stream>>>(out, lengths, P);
}

// Round 7
// 174.222 us; speedup vs baseline: 1.9533x; 1.9533x over previous
//
#include <hip/hip_runtime.h>
#include <hip/hip_bf16.h>
#include <stdint.h>

// SurrealEmbedding: B=8192, L=618, D=1910
// Decomposition: base[s] = S + sigma*D, S=(p+m)/2, D=(p-m)/2, sigma=+-1.
// hv[b] = P[n_b] + sum_l A_D[b,l] * D_l   (P = fp32 prefix table over S)
#define B_   8192
#define L_   618
#define D_   1910
#define KA   640          // K for the D-GEMM (padded L, multiple of 64)
#define NP   1920         // padded D (multiple of 128)
#define PSTRIDE 1920
#define NCHUNK 40         // 40 chunks x 16 = 640 >= L_

#define ALPHA_F 0.61803400516510009765625f   // float32(1/phi), exact bits

typedef __attribute__((ext_vector_type(8))) short short8;
typedef __attribute__((ext_vector_type(4))) float f32x4;

__device__ __forceinline__ unsigned short f2bf(float f) {
  union { float f; unsigned u; } v; v.f = f;
  unsigned u = v.u;
  return (unsigned short)((u + 0x7FFFu + ((u >> 16) & 1u)) >> 16);  // RNE
}

// ---------------------------------------------------------------------------
// prep_A: A_D[b][l] = (l<n) ? sigma*w_l : 0   (bf16; w_0=ALPHA, w_{l>=1}=1.0)
// ---------------------------------------------------------------------------
__global__ void prep_A(const int* __restrict__ signs, const int* __restrict__ lengths,
                       unsigned short* __restrict__ A) {
  int b = blockIdx.x;
  int n = lengths[b];
  const unsigned short w1 = 0x3F80u;          // bf16(1.0)
  const unsigned short wa = f2bf(ALPHA_F);    // bf16(ALPHA)
  for (int l = threadIdx.x; l < KA; l += blockDim.x) {
    unsigned short val = 0;
    if (l < L_ && l < n) {
      unsigned short w = (l == 0) ? wa : w1;
      int s = signs[b * L_ + l];
      val = s ? (unsigned short)(w | 0x8000u) : w;   // minus -> -w
    }
    A[(size_t)b * KA + l] = val;
  }
}

// ---------------------------------------------------------------------------
// prep_B: BT[d][l] = bf16((bp[l][d]-bm[l][d])/2), transposed via LDS tile so
// both global reads and writes are coalesced.  BT is [NP][KA] bf16.
// ---------------------------------------------------------------------------
__global__ void prep_B(const float* __restrict__ bp, const float* __restrict__ bm,
                       unsigned short* __restrict__ BT) {
  __shared__ unsigned short tile[64][65];
  int lt = threadIdx.x & 63;
  int wt = threadIdx.x >> 6;       // 0..3
  int l0 = blockIdx.y * 64, d0 = blockIdx.x * 64;
#pragma unroll
  for (int i = 0; i < 16; ++i) {
    int r = i * 4 + wt;            // l-offset within tile
    int l = l0 + r, d = d0 + lt;
    unsigned short v = 0;
    if (l < L_ && d < D_)
      v = f2bf(0.5f * (bp[(size_t)l * D_ + d] - bm[(size_t)l * D_ + d]));
    tile[lt][r] = v;               // [d-idx][l-idx]
  }
  __syncthreads();
#pragma unroll
  for (int i = 0; i < 16; ++i) {
    int rd = i * 4 + wt;           // d-offset within tile
    BT[(size_t)(d0 + rd) * KA + l0 + lt] = tile[rd][lt];
  }
}

// ---------------------------------------------------------------------------
// prefix_chunks: C[c][d] = sum_{l in chunk c} w_l * S_l[d]  (16 l per chunk)
// ---------------------------------------------------------------------------
__global__ void prefix_chunks(const float* __restrict__ bp, const float* __restrict__ bm,
                              float* __restrict__ C) {
  int d = blockIdx.x * 256 + threadIdx.x;
  if (d >= D_) return;
  int c = blockIdx.y;
  float s = 0.f;
#pragma unroll
  for (int i = 0; i < 16; ++i) {
    int l = c * 16 + i;
    if (l < L_) {
      float v = 0.5f * (bp[(size_t)l * D_ + d] + bm[(size_t)l * D_ + d]);
      s += (l == 0) ? ALPHA_F * v : v;
    }
  }
  C[(size_t)c * D_ + d] = s;
}

// ---------------------------------------------------------------------------
// prefix_emit: P[c*16+1+i][d] = sum of chunks < c + running prefix in chunk c.
// All 40 chunk-sum loads are independent (masked accumulate) -> pipelined.
// ---------------------------------------------------------------------------
__global__ void prefix_emit(const float* __restrict__ bp, const float* __restrict__ bm,
                            const float* __restrict__ C, float* __restrict__ P) {
  int d = blockIdx.x * 256 + threadIdx.x;
  if (d >= D_) return;
  int c = blockIdx.y;
  float off = 0.f;
#pragma unroll
  for (int cc = 0; cc < NCHUNK; ++cc) {
    float v = C[(size_t)cc * D_ + d];
    off += (cc < c) ? v : 0.f;
  }
#pragma unroll
  for (int i = 0; i < 16; ++i) {
    int l = c * 16 + i;
    float v = 0.f;
    if (l < L_) {
      v = 0.5f * (bp[(size_t)l * D_ + d] + bm[(size_t)l * D_ + d]);
      v = (l == 0) ? ALPHA_F * v : v;
    }
    off += v;
    P[(size_t)(l + 1) * PSTRIDE + d] = off;
  }
}

// ---------------------------------------------------------------------------
// GEMM: C[8192][1920] = A_D[8192][640] * D[640][1920] (D given transposed).
// 128x128 tile, BK=64, 4 waves of 64x64, 16x16x32 bf16 MFMA, XOR-swizzled LDS.
// ---------------------------------------------------------------------------
__global__ __launch_bounds__(256)
void gemm_kernel(const unsigned short* __restrict__ A2,
                 const unsigned short* __restrict__ BT,
                 float* __restrict__ out) {
  __shared__ __align__(16) short As[128 * 64];
  __shared__ __align__(16) short Bs[128 * 64];

  const int tid = threadIdx.x;
  const int l   = tid & 63;
  const int w   = tid >> 6;
  const int wm  = w >> 1, wn = w & 1;
  const int m0  = blockIdx.y * 128;
  const int n0  = blockIdx.x * 128;

  f32x4 acc[4][4] = {};
  short8 ar[4], br[4];

#pragma unroll
  for (int i = 0; i < 4; ++i) {
    int idx = (i * 256 + tid) * 8;
    int r = idx >> 6, c = idx & 63;
    ar[i] = *(const short8*)(A2 + (size_t)(m0 + r) * KA + c);
    br[i] = *(const short8*)(BT + (size_t)(n0 + r) * KA + c);
  }

  const int NT = KA / 64;
  for (int kt = 0; kt < NT; ++kt) {
    __syncthreads();
#pragma unroll
    for (int i = 0; i < 4; ++i) {
      int idx = (i * 256 + tid) * 8;
      int r = idx >> 6;
      int off = idx ^ ((r & 7) << 3);      // T2 swizzle, 16B slots (short units)
      *(short8*)(As + off) = ar[i];
      *(short8*)(Bs + off) = br[i];
    }
    __syncthreads();

    if (kt + 1 < NT) {
      int k0 = (kt + 1) * 64;
#pragma unroll
      for (int i = 0; i < 4; ++i) {
        int idx = (i * 256 + tid) * 8;
        int r = idx >> 6, c = idx & 63;
        ar[i] = *(const short8*)(A2 + (size_t)(m0 + r) * KA + k0 + c);
        br[i] = *(const short8*)(BT + (size_t)(n0 + r) * KA + k0 + c);
      }
    }

#pragma unroll
    for (int kk = 0; kk < 64; kk += 32) {
      const int cs = kk + ((l >> 4) << 3);        // short col within tile row
      short8 af[4], bf[4];
#pragma unroll
      for (int m = 0; m < 4; ++m) {
        int r = wm * 64 + m * 16 + (l & 15);
        af[m] = *(const short8*)(As + (r * 64 + (cs ^ ((r & 7) << 3))));
      }
#pragma unroll
      for (int n = 0; n < 4; ++n) {
        int r = wn * 64 + n * 16 + (l & 15);
        bf[n] = *(const short8*)(Bs + (r * 64 + (cs ^ ((r & 7) << 3))));
      }
#pragma unroll
      for (int m = 0; m < 4; ++m)
#pragma unroll
        for (int n = 0; n < 4; ++n)
          acc[m][n] = __builtin_amdgcn_mfma_f32_16x16x32_bf16(af[m], bf[n], acc[m][n], 0, 0, 0);
    }
  }

  // epilogue: C/D layout col = lane&15, row = (lane>>4)*4 + reg
  const int rl = l >> 4, cl = l & 15;
#pragma unroll
  for (int m = 0; m < 4; ++m) {
#pragma unroll
    for (int n = 0; n < 4; ++n) {
      int col = n0 + wn * 64 + n * 16 + cl;
      if (col < D_) {
        int rbase = m0 + wm * 64 + m * 16 + rl * 4;
#pragma unroll
        for (int q = 0; q < 4; ++q)
          out[(size_t)(rbase + q) * D_ + col] = acc[m][n][q];
      }
    }
  }
}

// ---------------------------------------------------------------------------
// normalize: v = gemm_out[b,:] + P[n_b,:];  out = v / max(||v||, eps-guard)
// ---------------------------------------------------------------------------
__global__ void normalize_kernel(float* __restrict__ out, const int* __restrict__ lengths,
                                 const float* __restrict__ P) {
  __shared__ float red[4];
  int b = blockIdx.x;
  int n = lengths[b];
  float* row = out + (size_t)b * D_;
  const float* prow = P + (size_t)n * PSTRIDE;
  float vals[8];
  float ss = 0.f;
#pragma unroll
  for (int j = 0; j < 8; ++j) {
    int d = threadIdx.x + j * 256;
    float v = 0.f;
    if (d < D_) v = row[d] + prow[d];
    vals[j] = v;
    ss += v * v;
  }
#pragma unroll
  for (int off = 32; off > 0; off >>= 1)
    ss += __shfl_down(ss, off, 64);
  int lane = threadIdx.x & 63, wv = threadIdx.x >> 6;
  if (lane == 0) red[wv] = ss;
  __syncthreads();
  float tot = red[0] + red[1] + red[2] + red[3];
  float inv = (tot > 0.f) ? (1.0f / sqrtf(tot)) : 1.0f;
#pragma unroll
  for (int j = 0; j < 8; ++j) {
    int d = threadIdx.x + j * 256;
    if (d < D_) row[d] = vals[j] * inv;
  }
}

extern "C" void kernel_launch(void* const* d_in, const int* in_sizes, int n_in,
                              void* d_out, int out_size, void* d_ws, size_t ws_size,
                              hipStream_t stream) {
  const int*   signs   = (const int*)d_in[0];
  const int*   lengths = (const int*)d_in[1];
  const float* bp      = (const float*)d_in[2];
  const float* bm      = (const float*)d_in[3];
  float*       out     = (float*)d_out;

  unsigned short* A  = (unsigned short*)d_ws;                 // [8192][640] bf16 = 10.49 MB
  unsigned short* BT = A + (size_t)B_ * KA;                   // [1920][640] bf16 =  2.46 MB
  float*          P  = (float*)(BT + (size_t)NP * KA);        // [656][1920] f32  =  5.04 MB
  float*          C  = P + (size_t)656 * PSTRIDE;             // [40][1910]  f32  =  0.31 MB

  prep_A<<<B_, 256, 0, stream>>>(signs, lengths, A);
  prep_B<<<dim3(NP / 64, KA / 64), 256, 0, stream>>>(bp, bm, BT);
  prefix_chunks<<<dim3(8, NCHUNK), 256, 0, stream>>>(bp, bm, C);
  prefix_emit<<<dim3(8, NCHUNK), 256, 0, stream>>>(bp, bm, C, P);
  gemm_kernel<<<dim3(NP / 128, B_ / 128), 256, 0, stream>>>(A, BT, out);
  normalize_kernel<<<B_, 256, 0, stream>>>(out, lengths, P);
}